// Round 1
// baseline (825.577 us; speedup 1.0000x reference)
//
#include <hip/hip_runtime.h>

// Haar wavedec2(level=1) + waverec2 == per-2x2-block forward+inverse Haar.
// Computed exactly in the reference's fp32 op order so absmax vs the JAX/np
// reference is ~ULP-level. Pure streaming kernel: 1 read + 1 write per elem.

#define W 512           // last dim (cols)
#define HALF_W 256      // row pairs per image = H/2, col quads per row = W/4
#define INV_SQRT2 0.7071067811865476f

__global__ __launch_bounds__(256) void haar_roundtrip_kernel(
    const float* __restrict__ x, float* __restrict__ out, int total_threads) {
    int idx = blockIdx.x * blockDim.x + threadIdx.x;
    if (idx >= total_threads) return;

    // thread -> (image n, row-pair rp in [0,256), col-quad cq in [0,128))
    int cq = idx & 127;
    int rp = (idx >> 7) & 255;
    int n  = idx >> 15;

    long base = (long)n * (W * W) + (long)(rp * 2) * W + cq * 4;

    const float4 top = *(const float4*)(x + base);        // row 2*rp
    const float4 bot = *(const float4*)(x + base + W);    // row 2*rp+1

    float4 otop, obot;

    // ---- block 0: (top.x, top.y, bot.x, bot.y) ----
    {
        float a = top.x, b = top.y, c = bot.x, d = bot.y;
        // row DWT (pairs along rows axis): e=row even, o=row odd
        float lo0 = (a + c) * INV_SQRT2, lo1 = (b + d) * INV_SQRT2;
        float hi0 = (a - c) * INV_SQRT2, hi1 = (b - d) * INV_SQRT2;
        // col DWT
        float ll = (lo0 + lo1) * INV_SQRT2, lh = (lo0 - lo1) * INV_SQRT2;
        float hl = (hi0 + hi1) * INV_SQRT2, hh = (hi0 - hi1) * INV_SQRT2;
        // col IDWT
        float rlo0 = (ll + lh) * INV_SQRT2, rlo1 = (ll - lh) * INV_SQRT2;
        float rhi0 = (hl + hh) * INV_SQRT2, rhi1 = (hl - hh) * INV_SQRT2;
        // row IDWT
        otop.x = (rlo0 + rhi0) * INV_SQRT2;
        otop.y = (rlo1 + rhi1) * INV_SQRT2;
        obot.x = (rlo0 - rhi0) * INV_SQRT2;
        obot.y = (rlo1 - rhi1) * INV_SQRT2;
    }

    // ---- block 1: (top.z, top.w, bot.z, bot.w) ----
    {
        float a = top.z, b = top.w, c = bot.z, d = bot.w;
        float lo0 = (a + c) * INV_SQRT2, lo1 = (b + d) * INV_SQRT2;
        float hi0 = (a - c) * INV_SQRT2, hi1 = (b - d) * INV_SQRT2;
        float ll = (lo0 + lo1) * INV_SQRT2, lh = (lo0 - lo1) * INV_SQRT2;
        float hl = (hi0 + hi1) * INV_SQRT2, hh = (hi0 - hi1) * INV_SQRT2;
        float rlo0 = (ll + lh) * INV_SQRT2, rlo1 = (ll - lh) * INV_SQRT2;
        float rhi0 = (hl + hh) * INV_SQRT2, rhi1 = (hl - hh) * INV_SQRT2;
        otop.z = (rlo0 + rhi0) * INV_SQRT2;
        otop.w = (rlo1 + rhi1) * INV_SQRT2;
        obot.z = (rlo0 - rhi0) * INV_SQRT2;
        obot.w = (rlo1 - rhi1) * INV_SQRT2;
    }

    *(float4*)(out + base)     = otop;
    *(float4*)(out + base + W) = obot;
}

extern "C" void kernel_launch(void* const* d_in, const int* in_sizes, int n_in,
                              void* d_out, int out_size, void* d_ws, size_t ws_size,
                              hipStream_t stream) {
    const float* x = (const float*)d_in[0];
    float* out = (float*)d_out;

    int total_elems = in_sizes[0];              // 16*32*512*512 = 134217728
    int total_threads = total_elems / 8;        // 8 elements per thread (2x4)
    int block = 256;
    int grid = (total_threads + block - 1) / block;

    haar_roundtrip_kernel<<<grid, block, 0, stream>>>(x, out, total_threads);
}